// Round 13
// baseline (12.228 us; speedup 1.0000x reference)
//
#include <hip/hip_runtime.h>
#include <math.h>

#define Hh 64
#define Ww 64
#define Nn 512
#define Bb 32
#define NPIX (Hh * Ww)            // 4096
#define TCUT 16.0f                // cull where quadratic (exp2 domain) < -TCUT

#define L2E 1.4426950408889634f   // log2(e)

__device__ __forceinline__ float fast_sigmoid(float x) {
    float e = __builtin_amdgcn_exp2f(-x * L2E);
    return __builtin_amdgcn_rcpf(1.0f + e);
}
__device__ __forceinline__ float fast_tanh(float x) {
    // tanh(x) = 2*sigmoid(2x) - 1 = 2*rcp(1+e^{-2x}) - 1
    float e = __builtin_amdgcn_exp2f(x * (-2.0f * L2E));
    return fmaf(2.0f, __builtin_amdgcn_rcpf(1.0f + e), -1.0f);
}

// Single fused kernel. Block (512 thr = 8 waves) = (batch, tile-pair {tp, 63-tp}).
// Complementary pairing: heavy corner tiles pair with light center tiles.
// Phase 1 : prep 1 gaussian/thread into LDS.
// Phase 2a: wave w ballot-culls quarter (w&3) of N for tile (w>>2) -> seg[w].
// Phase 2b: deterministic compaction into contiguous per-tile lists tlist[2],
//           then waves are split between tiles PROPORTIONALLY to survivor
//           counts (n0 waves on tile0, 8-n0 on tile1), each taking a strided
//           slice -> every wave does ~(c0+c1)/8 iterations (balance).
// Phase 3 : survivor loop (LDS broadcast reads).
// Phase 4 : rank>0 waves dump acc; rank==0 wave per tile combines + stores.
__global__ __launch_bounds__(512, 8) void gs_fused(const float* __restrict__ data,
                                                   const float* __restrict__ opacity,
                                                   float* __restrict__ out) {
    __shared__ float4 sA[Nn];            // 8 KB  {q0,q1,q2,a2}
    __shared__ float4 sB[Nn];            // 8 KB  {b2,c2,ocr,ocg}
    __shared__ float  sC[Nn];            // 2 KB  ocb
    __shared__ float4 sD[Nn];            // 8 KB  {px,py,xext,yext}
    __shared__ short  seg[8][128];       // 2 KB  per-wave cull segments
    __shared__ short  tlist[2][Nn];      // 2 KB  compacted per-tile lists
    __shared__ int    scnt[8];           // 32 B
    __shared__ float  comb[6][3][64];    // 4.5 KB

    int bid = blockIdx.x;
    int tp  = bid & 31;                  // tile-pair id (low bits: XCD spread)
    int b   = bid >> 5;
    int t   = threadIdx.x;               // 0..511
    int base = b * Nn;

    // ---- Phase 1: prep one gaussian per thread ----
    {
        int n = t;
        const float4* dp = (const float4*)(data) + (size_t)(base + n) * 2;
        float4 d0 = dp[0];
        float4 d1 = dp[1];

        float xy0 = fast_tanh(d0.x);
        float xy1 = fast_tanh(d0.y);
        float s0 = fabsf(d0.z) + 0.3f;
        float s1 = fabsf(d0.w) + 0.3f;
        float u  = fast_sigmoid(d1.x);            // theta/(2*pi) in (0,1)
        float c  = __builtin_amdgcn_cosf(u);      // hw sin/cos take revolutions
        float s  = __builtin_amdgcn_sinf(u);

        float px = 0.5f * ((xy0 + 1.0f) * (float)Ww - 1.0f);
        float py = 0.5f * ((xy1 + 1.0f) * (float)Hh - 1.0f);

        float s0sq = s0 * s0, s1sq = s1 * s1;
        float cov_a = c * c * s0sq + s * s * s1sq;
        float cov_b = c * s * (s0sq - s1sq);
        float cov_c = s * s * s0sq + c * c * s1sq;
        float det = cov_a * cov_c - cov_b * cov_b;
        float inv = __builtin_amdgcn_rcpf(det);
        float con_a = cov_c * inv;
        float con_b = -cov_b * inv;
        float con_c = cov_a * inv;

        float a2 = -0.5f * con_a * L2E;          // dx^2 coeff (<0)
        float b2 = -con_b * L2E;                 // dx*dy coeff
        float c2 = -0.5f * con_c * L2E;          // dy^2 coeff (<0)

        float q1 = -(2.0f * a2 * px + b2 * py);
        float q2 = -(2.0f * c2 * py + b2 * px);
        float q0 = a2 * px * px + b2 * px * py + c2 * py * py;

        float det2 = 4.0f * a2 * c2 - b2 * b2;   // > 0 (neg definite)
        float rinv = __builtin_amdgcn_rcpf(det2);
        float xext = __builtin_amdgcn_sqrtf(fmaxf(4.0f * TCUT * (-c2) * rinv, 0.0f));
        float yext = __builtin_amdgcn_sqrtf(fmaxf(4.0f * TCUT * (-a2) * rinv, 0.0f));

        float op = opacity[n];

        sA[n] = make_float4(q0, q1, q2, a2);
        sB[n] = make_float4(b2, c2, op * d1.y, op * d1.z);
        sC[n] = op * d1.w;
        sD[n] = make_float4(px, py, xext, yext);
    }
    __syncthreads();

    int w    = t >> 6;                   // 0..7
    int lane = t & 63;
    int tsel = w >> 2;                   // which tile of the pair this wave culls
    int q    = w & 3;                    // N-quarter
    int ctile = tsel ? (63 - tp) : tp;   // complementary pairing
    int ctx0 = (ctile & 7) * 8;
    int cty0 = (ctile >> 3) * 8;

    // ---- Phase 2a: cull quarter q for tile tsel ----
    float fxq0 = (float)ctx0, fxq1 = (float)(ctx0 + 7);
    float fyq0 = (float)cty0, fyq1 = (float)(cty0 + 7);
    int cnt = 0;
#pragma unroll
    for (int r = 0; r < 2; ++r) {
        int ln = q * 128 + r * 64 + lane;
        float4 D = sD[ln];
        bool keep = (D.x + D.z >= fxq0) && (D.x - D.z <= fxq1) &&
                    (D.y + D.w >= fyq0) && (D.y - D.w <= fyq1);
        unsigned long long m = __ballot(keep);
        int pos = (int)__popcll(m & ((1ull << lane) - 1ull));
        if (keep) seg[w][cnt + pos] = (short)ln;
        cnt += (int)__popcll(m);
    }
    if (lane == 0) scnt[w] = cnt;
    __syncthreads();

    // ---- Phase 2b: deterministic compaction into per-tile lists ----
    int c0 = scnt[0] + scnt[1] + scnt[2] + scnt[3];
    int c1 = scnt[4] + scnt[5] + scnt[6] + scnt[7];
    int off = 0;
    for (int j = tsel * 4; j < w; ++j) off += scnt[j];
    for (int i = lane; i < cnt; i += 64) tlist[tsel][off + i] = seg[w][i];
    __syncthreads();

    // proportional wave->tile split
    int total = c0 + c1;
    int n0 = 4;
    if (total > 0) {
        n0 = (int)(8.0f * (float)c0 / (float)total + 0.5f);
        n0 = n0 < 1 ? 1 : (n0 > 7 ? 7 : n0);
    }
    int tt, rank, nt;
    if (w < n0) { tt = 0; rank = w;      nt = n0;     }
    else        { tt = 1; rank = w - n0; nt = 8 - n0; }
    int ct    = tt ? c1 : c0;
    int ttile = tt ? (63 - tp) : tp;
    int tx0 = (ttile & 7) * 8;
    int ty0 = (ttile >> 3) * 8;

    // ---- Phase 3: strided survivor loop ----
    float fx = (float)(tx0 + (lane & 7));
    float fy = (float)(ty0 + (lane >> 3));
    float fx2 = fx * fx;
    float fxy = fx * fy;
    float fy2 = fy * fy;

    float accr = 0.0f, accg = 0.0f, accb = 0.0f;
#pragma unroll 4
    for (int idx = rank; idx < ct; idx += nt) {
        int ln = tlist[tt][idx];
        float4 A  = sA[ln];    // q0,q1,q2,a2
        float4 Bv = sB[ln];    // b2,c2,ocr,ocg
        float  ob = sC[ln];    // ocb
        float sgm = fmaf(A.y, fx, A.x);
        sgm = fmaf(A.z, fy, sgm);
        sgm = fmaf(A.w, fx2, sgm);
        sgm = fmaf(Bv.x, fxy, sgm);
        sgm = fmaf(Bv.y, fy2, sgm);
        float e = __builtin_amdgcn_exp2f(sgm);
        accr = fmaf(e, Bv.z, accr);
        accg = fmaf(e, Bv.w, accg);
        accb = fmaf(e, ob, accb);
    }

    // ---- Phase 4: combine per tile, rank==0 waves store ----
    if (rank > 0) {
        int slot = tt ? (n0 - 1 + rank - 1) : (rank - 1);
        comb[slot][0][lane] = accr;
        comb[slot][1][lane] = accg;
        comb[slot][2][lane] = accb;
    }
    __syncthreads();
    if (rank == 0) {
        int s0 = tt ? (n0 - 1) : 0;
        int ns = (tt ? (8 - n0) : n0) - 1;
        for (int j = 0; j < ns; ++j) {
            accr += comb[s0 + j][0][lane];
            accg += comb[s0 + j][1][lane];
            accb += comb[s0 + j][2][lane];
        }
        int pix = (ty0 + (lane >> 3)) * Ww + tx0 + (lane & 7);
        size_t obase = (size_t)b * 3 * NPIX + (size_t)pix;
        out[obase]            = accr;
        out[obase + NPIX]     = accg;
        out[obase + 2 * NPIX] = accb;
    }
}

extern "C" void kernel_launch(void* const* d_in, const int* in_sizes, int n_in,
                              void* d_out, int out_size, void* d_ws, size_t ws_size,
                              hipStream_t stream) {
    const float* data    = (const float*)d_in[0];
    const float* opacity = (const float*)d_in[1];
    float* out = (float*)d_out;

    gs_fused<<<Bb * 32, 512, 0, stream>>>(data, opacity, out);
}

// Round 14
// 10.712 us; speedup vs baseline: 1.1415x; 1.1415x over previous
//
#include <hip/hip_runtime.h>
#include <math.h>

#define Hh 64
#define Ww 64
#define Nn 512
#define Bb 32
#define NPIX (Hh * Ww)            // 4096
#define TCUT 12.0f                // cull where quadratic (exp2 domain) < -TCUT

#define L2E 1.4426950408889634f   // log2(e)

__device__ __forceinline__ float fast_sigmoid(float x) {
    float e = __builtin_amdgcn_exp2f(-x * L2E);
    return __builtin_amdgcn_rcpf(1.0f + e);
}
__device__ __forceinline__ float fast_tanh(float x) {
    // tanh(x) = 2*sigmoid(2x) - 1 = 2*rcp(1+e^{-2x}) - 1
    float e = __builtin_amdgcn_exp2f(x * (-2.0f * L2E));
    return fmaf(2.0f, __builtin_amdgcn_rcpf(1.0f + e), -1.0f);
}

// Single fused kernel (R12 structure — best measured: 10.84 us).
// Block (512 thr = 8 waves) = (batch, pair of adjacent 8x8 tiles).
// 1024 blocks; 33 KB LDS -> 4 blocks/CU = 32 waves/CU = occupancy cap.
// Phase 1: each thread preps ONE gaussian into LDS (cheap transcendentals:
//   exp2/rcp sigmoid+tanh; theta=2pi*sigmoid(z) -> hw sin/cos in revolutions).
// Phase 2: wave w: tile_sel=w>>2, quarter q=w&3; ballot-cull 128 gaussians.
// Phase 3: survivor loop (LDS broadcast reads), accumulate rgb.
// Phase 4: q>0 waves dump acc to LDS; q==0 waves combine + store.
__global__ __launch_bounds__(512, 8) void gs_fused(const float* __restrict__ data,
                                                   const float* __restrict__ opacity,
                                                   float* __restrict__ out) {
    __shared__ float4 sA[Nn];               // 8 KB  {q0,q1,q2,a2}
    __shared__ float4 sB[Nn];               // 8 KB  {b2,c2,ocr,ocg}
    __shared__ float  sC[Nn];               // 2 KB  ocb
    __shared__ float4 sD[Nn];               // 8 KB  {px,py,xext,yext}
    __shared__ short  slist[8][Nn / 4];     // 2 KB
    __shared__ float  comb[2][3][3][64];    // 4.5 KB  [tile][q-1][ch][lane]

    int bid = blockIdx.x;
    int tp  = bid & 31;                  // tile-pair 0..31 (low bits: XCD spread)
    int b   = bid >> 5;
    int t   = threadIdx.x;               // 0..511
    int base = b * Nn;

    // ---- Phase 1: prep one gaussian per thread, straight into LDS ----
    {
        int n = t;
        const float4* dp = (const float4*)(data) + (size_t)(base + n) * 2;
        float4 d0 = dp[0];   // data[...,0..3]
        float4 d1 = dp[1];   // data[...,4..7]

        float xy0 = fast_tanh(d0.x);
        float xy1 = fast_tanh(d0.y);
        float s0 = fabsf(d0.z) + 0.3f;
        float s1 = fabsf(d0.w) + 0.3f;
        float u  = fast_sigmoid(d1.x);            // theta/(2*pi) in (0,1)
        float c  = __builtin_amdgcn_cosf(u);      // cos(theta), revolutions
        float s  = __builtin_amdgcn_sinf(u);      // sin(theta)

        float px = 0.5f * ((xy0 + 1.0f) * (float)Ww - 1.0f);
        float py = 0.5f * ((xy1 + 1.0f) * (float)Hh - 1.0f);

        float s0sq = s0 * s0, s1sq = s1 * s1;
        float cov_a = c * c * s0sq + s * s * s1sq;
        float cov_b = c * s * (s0sq - s1sq);
        float cov_c = s * s * s0sq + c * c * s1sq;
        float det = cov_a * cov_c - cov_b * cov_b;
        float inv = __builtin_amdgcn_rcpf(det);
        float con_a = cov_c * inv;
        float con_b = -cov_b * inv;
        float con_c = cov_a * inv;

        float a2 = -0.5f * con_a * L2E;          // dx^2 coeff (<0)
        float b2 = -con_b * L2E;                 // dx*dy coeff
        float c2 = -0.5f * con_c * L2E;          // dy^2 coeff (<0)

        // expand around (px,py)
        float q1 = -(2.0f * a2 * px + b2 * py);
        float q2 = -(2.0f * c2 * py + b2 * px);
        float q0 = a2 * px * px + b2 * px * py + c2 * py * py;

        // exact bbox of { q(dx,dy) >= -TCUT }
        float det2 = 4.0f * a2 * c2 - b2 * b2;   // > 0 (neg definite)
        float rinv = __builtin_amdgcn_rcpf(det2);
        float xext = __builtin_amdgcn_sqrtf(fmaxf(4.0f * TCUT * (-c2) * rinv, 0.0f));
        float yext = __builtin_amdgcn_sqrtf(fmaxf(4.0f * TCUT * (-a2) * rinv, 0.0f));

        float op = opacity[n];

        sA[n] = make_float4(q0, q1, q2, a2);
        sB[n] = make_float4(b2, c2, op * d1.y, op * d1.z);
        sC[n] = op * d1.w;
        sD[n] = make_float4(px, py, xext, yext);
    }
    __syncthreads();

    // ---- Phase 2: wave w culls its N-quarter for its tile ----
    int w        = t >> 6;               // 0..7
    int lane     = t & 63;
    int tile_sel = w >> 2;               // 0/1: which tile of the pair
    int q        = w & 3;                // N-quarter
    int tile     = (tp << 1) | tile_sel; // 0..63
    int tx0      = (tile & 7) * 8;
    int ty0      = (tile >> 3) * 8;
    float fxq0 = (float)tx0, fxq1 = (float)(tx0 + 7);
    float fyq0 = (float)ty0, fyq1 = (float)(ty0 + 7);

    short* wl = slist[w];
    int cnt = 0;
#pragma unroll
    for (int r = 0; r < 2; ++r) {
        int ln = q * 128 + r * 64 + lane;
        float4 D = sD[ln];               // px, py, xext, yext
        bool keep = (D.x + D.z >= fxq0) && (D.x - D.z <= fxq1) &&
                    (D.y + D.w >= fyq0) && (D.y - D.w <= fyq1);
        unsigned long long m = __ballot(keep);
        int pos = (int)__popcll(m & ((1ull << lane) - 1ull));
        if (keep) wl[cnt + pos] = (short)ln;
        cnt += (int)__popcll(m);
    }
    // slist is wave-private (written+read by same wave): no barrier needed

    // ---- Phase 3: survivor loop ----
    float fx = (float)(tx0 + (lane & 7));
    float fy = (float)(ty0 + (lane >> 3));
    float fx2 = fx * fx;
    float fxy = fx * fy;
    float fy2 = fy * fy;

    float accr = 0.0f, accg = 0.0f, accb = 0.0f;
#pragma unroll 4
    for (int i = 0; i < cnt; ++i) {
        int ln = wl[i];
        float4 A  = sA[ln];    // q0,q1,q2,a2
        float4 Bv = sB[ln];    // b2,c2,ocr,ocg
        float  ob = sC[ln];    // ocb
        float sgm = fmaf(A.y, fx, A.x);
        sgm = fmaf(A.z, fy, sgm);
        sgm = fmaf(A.w, fx2, sgm);
        sgm = fmaf(Bv.x, fxy, sgm);
        sgm = fmaf(Bv.y, fy2, sgm);
        float e = __builtin_amdgcn_exp2f(sgm);
        accr = fmaf(e, Bv.z, accr);
        accg = fmaf(e, Bv.w, accg);
        accb = fmaf(e, ob, accb);
    }

    // ---- Phase 4: combine N-quarters per tile, q==0 waves store ----
    if (q > 0) {
        comb[tile_sel][q - 1][0][lane] = accr;
        comb[tile_sel][q - 1][1][lane] = accg;
        comb[tile_sel][q - 1][2][lane] = accb;
    }
    __syncthreads();
    if (q == 0) {
        accr += comb[tile_sel][0][0][lane] + comb[tile_sel][1][0][lane] + comb[tile_sel][2][0][lane];
        accg += comb[tile_sel][0][1][lane] + comb[tile_sel][1][1][lane] + comb[tile_sel][2][1][lane];
        accb += comb[tile_sel][0][2][lane] + comb[tile_sel][1][2][lane] + comb[tile_sel][2][2][lane];
        int pix = (ty0 + (lane >> 3)) * Ww + tx0 + (lane & 7);
        size_t obase = (size_t)b * 3 * NPIX + (size_t)pix;
        out[obase]            = accr;
        out[obase + NPIX]     = accg;
        out[obase + 2 * NPIX] = accb;
    }
}

extern "C" void kernel_launch(void* const* d_in, const int* in_sizes, int n_in,
                              void* d_out, int out_size, void* d_ws, size_t ws_size,
                              hipStream_t stream) {
    const float* data    = (const float*)d_in[0];
    const float* opacity = (const float*)d_in[1];
    float* out = (float*)d_out;

    gs_fused<<<Bb * 32, 512, 0, stream>>>(data, opacity, out);
}